// Round 1
// baseline (522.193 us; speedup 1.0000x reference)
//
#include <hip/hip_runtime.h>
#include <math.h>

// CrossDomainBridge — MI355X fp32 baseline.
//
// Math shortcut (exact, not an approximation):
//   s = softmax(QK^T, axis=-1) ==> every row sums to 1 ==> mean(s,(1,2)) = 1/2048
//   ==> corr == 1/2048 everywhere, dw == 1/8, corr_mean == 1/2048.
//   The Wk/Wq GEMMs and the [B,2048,2048] softmax never need to run.
//   gate bias folds to: bg_eff[c] = bg[c] + (1/2048)*(Wg[128,c]+Wg[129,c]+Wg[130,c])
//
// Shapes: B=8 N=2048 C=64 A=256 F=128; tokens = 16384.
// d_out layout (floats): out[2097152] corr[72] dw0[8] dw1[8] dw2[8] enh0 enh1 enh2
//
// Kernel design: token-parallel, TOK=16 tokens/block, 256 threads.
// Weights streamed through a 32KB LDS chunk buffer (keeps block <=64KB LDS
// -> 2 blocks/CU). Phase layouts keep LDS reads broadcast or stride-1.

#define TOK 16

__global__ void const_kernel(float* __restrict__ dst) {
    int i = threadIdx.x;
    if (i < 72) dst[i] = 4.8828125e-4f;        // corr = 1/2048 (exact fp32)
    else if (i < 96) dst[i] = 0.125f;          // dw0,dw1,dw2 = 1/8
}

// One domain: enh = (a@Wt+bt) * sigmoid((a@Wt+bt)@Wg0 + bg_eff) * 0.125
// where a = LN(x@Wd+bd, g1, b1)
__global__ __launch_bounds__(256) void domain_kernel(
    const float* __restrict__ x,    // [16384,64]
    const float* __restrict__ Wd,   // [64,256]
    const float* __restrict__ bd,   // [256]
    const float* __restrict__ g1,   // [256]
    const float* __restrict__ b1,   // [256]
    const float* __restrict__ Wt,   // [256,128]
    const float* __restrict__ bt,   // [128]
    const float* __restrict__ Wg,   // [131,128]
    const float* __restrict__ bg,   // [128]
    float* __restrict__ enh)        // [16384,128]
{
    extern __shared__ float lds[];
    float* Wbuf  = lds;                  // 8192 floats (32KB) weight chunk
    float* albuf = Wbuf + 8192;          // [TOK][256] aligned rows (16KB)
    float* xbuf  = albuf + TOK * 256;    // [TOK][64] x rows (4KB)
    float* tbuf  = xbuf + TOK * 64;      // [TOK][128] t rows (8KB)
    float* stats = tbuf + TOK * 128;     // [16][2]

    const int tid  = threadIdx.x;
    const int row0 = blockIdx.x * TOK;

    // stage x rows
    for (int i = tid; i < TOK * 64; i += 256) xbuf[i] = x[row0 * 64 + i];

    // ---- Phase A: z = x @ Wd + bd (col c = tid, 16 rows/thread) ----
    {
        float accA[TOK];
        const float bv = bd[tid];
        #pragma unroll
        for (int r = 0; r < TOK; ++r) accA[r] = bv;
        for (int ch = 0; ch < 2; ++ch) {            // K chunks of 32 (32*256 floats)
            for (int i = tid; i < 8192; i += 256) Wbuf[i] = Wd[ch * 8192 + i];
            __syncthreads();
            const int kb = ch * 32;
            for (int k = 0; k < 32; ++k) {
                const float w = Wbuf[k * 256 + tid];
                #pragma unroll
                for (int r = 0; r < TOK; ++r)
                    accA[r] += xbuf[r * 64 + kb + k] * w;
            }
            __syncthreads();
        }
        #pragma unroll
        for (int r = 0; r < TOK; ++r) albuf[r * 256 + tid] = accA[r];
    }
    __syncthreads();

    // ---- LN stats per row (4 waves x 4 rows, float4 per lane) ----
    {
        const int wave = tid >> 6, lane = tid & 63;
        for (int rr = 0; rr < TOK / 4; ++rr) {
            const int r = wave * (TOK / 4) + rr;
            const float4 v = *(const float4*)&albuf[r * 256 + lane * 4];
            float s  = v.x + v.y + v.z + v.w;
            float ss = v.x * v.x + v.y * v.y + v.z * v.z + v.w * v.w;
            #pragma unroll
            for (int off = 32; off >= 1; off >>= 1) {
                s  += __shfl_xor(s, off);
                ss += __shfl_xor(ss, off);
            }
            if (lane == 0) {
                const float m   = s * (1.f / 256.f);
                const float var = ss * (1.f / 256.f) - m * m;
                stats[r * 2]     = m;
                stats[r * 2 + 1] = rsqrtf(var + 1e-3f);
            }
        }
    }
    __syncthreads();
    {   // normalize in place
        const float gv = g1[tid], bv = b1[tid];
        #pragma unroll
        for (int r = 0; r < TOK; ++r) {
            const float m = stats[r * 2], rs = stats[r * 2 + 1];
            albuf[r * 256 + tid] = (albuf[r * 256 + tid] - m) * rs * gv + bv;
        }
    }
    __syncthreads();

    // ---- Phase T: t = a @ Wt + bt (c = tid&127, 8 rows/thread) ----
    const int c  = tid & 127;
    const int rg = tid >> 7;
    float tacc[8];
    {
        const float bv = bt[c];
        #pragma unroll
        for (int j = 0; j < 8; ++j) tacc[j] = bv;
        for (int ch = 0; ch < 4; ++ch) {            // K chunks of 64 (64*128 floats)
            for (int i = tid; i < 8192; i += 256) Wbuf[i] = Wt[ch * 8192 + i];
            __syncthreads();
            const int kb = ch * 64;
            for (int k = 0; k < 64; ++k) {
                const float w = Wbuf[k * 128 + c];
                #pragma unroll
                for (int j = 0; j < 8; ++j)
                    tacc[j] += albuf[(rg * 8 + j) * 256 + kb + k] * w;
            }
            __syncthreads();
        }
        #pragma unroll
        for (int j = 0; j < 8; ++j) tbuf[(rg * 8 + j) * 128 + c] = tacc[j];
    }
    __syncthreads();

    // ---- Phase G: z = t @ Wg0 + bg_eff; e = t*sigmoid(z)*0.125 ----
    {
        const float bge = bg[c] + 4.8828125e-4f *
            (Wg[128 * 128 + c] + Wg[129 * 128 + c] + Wg[130 * 128 + c]);
        float zacc[8];
        #pragma unroll
        for (int j = 0; j < 8; ++j) zacc[j] = bge;
        for (int ch = 0; ch < 2; ++ch) {            // K chunks of 64
            for (int i = tid; i < 8192; i += 256) Wbuf[i] = Wg[ch * 8192 + i];
            __syncthreads();
            const int kb = ch * 64;
            for (int k = 0; k < 64; ++k) {
                const float w = Wbuf[k * 128 + c];
                #pragma unroll
                for (int j = 0; j < 8; ++j)
                    zacc[j] += tbuf[(rg * 8 + j) * 128 + kb + k] * w;
            }
            __syncthreads();
        }
        #pragma unroll
        for (int j = 0; j < 8; ++j) {
            const float gate = 1.f / (1.f + expf(-zacc[j]));
            enh[(row0 + rg * 8 + j) * 128 + c] = tacc[j] * gate * 0.125f;
        }
    }
}

// fused = sum_d enh_d @ Wfu_d + bfu; out = LN(fused@Wdf+bdf, g2, b2)
__global__ __launch_bounds__(256) void fuse_kernel(
    const float* __restrict__ enh0, const float* __restrict__ enh1,
    const float* __restrict__ enh2,
    const float* __restrict__ Wfu, const float* __restrict__ bfu,
    const float* __restrict__ Wdf, const float* __restrict__ bdf,
    const float* __restrict__ g2,  const float* __restrict__ b2,
    float* __restrict__ out)
{
    extern __shared__ float lds[];
    float* Wbuf  = lds;                  // 8192 floats
    float* ebuf  = Wbuf + 8192;          // [TOK][128]
    float* fbuf  = ebuf + TOK * 128;     // [TOK][128]
    float* stats = fbuf + TOK * 128;     // [16][2]

    const int tid  = threadIdx.x;
    const int row0 = blockIdx.x * TOK;
    const int c    = tid & 127;
    const int rg   = tid >> 7;

    float facc[8];
    const float bv = bfu[c];
    #pragma unroll
    for (int j = 0; j < 8; ++j) facc[j] = bv;

    const float* enhs[3] = {enh0, enh1, enh2};
    #pragma unroll
    for (int d = 0; d < 3; ++d) {
        for (int i = tid; i < TOK * 128; i += 256) ebuf[i] = enhs[d][row0 * 128 + i];
        for (int ch = 0; ch < 2; ++ch) {
            for (int i = tid; i < 8192; i += 256) Wbuf[i] = Wfu[d * 16384 + ch * 8192 + i];
            __syncthreads();
            const int kb = ch * 64;
            for (int k = 0; k < 64; ++k) {
                const float w = Wbuf[k * 128 + c];
                #pragma unroll
                for (int j = 0; j < 8; ++j)
                    facc[j] += ebuf[(rg * 8 + j) * 128 + kb + k] * w;
            }
            __syncthreads();
        }
    }
    #pragma unroll
    for (int j = 0; j < 8; ++j) fbuf[(rg * 8 + j) * 128 + c] = facc[j];
    __syncthreads();

    // df = fused @ Wdf + bdf
    float dacc[8];
    const float bv2 = bdf[c];
    #pragma unroll
    for (int j = 0; j < 8; ++j) dacc[j] = bv2;
    for (int ch = 0; ch < 2; ++ch) {
        for (int i = tid; i < 8192; i += 256) Wbuf[i] = Wdf[ch * 8192 + i];
        __syncthreads();
        const int kb = ch * 64;
        for (int k = 0; k < 64; ++k) {
            const float w = Wbuf[k * 128 + c];
            #pragma unroll
            for (int j = 0; j < 8; ++j)
                dacc[j] += fbuf[(rg * 8 + j) * 128 + kb + k] * w;
        }
        __syncthreads();
    }
    #pragma unroll
    for (int j = 0; j < 8; ++j) ebuf[(rg * 8 + j) * 128 + c] = dacc[j];
    __syncthreads();

    // LN over 128 per row
    {
        const int wave = tid >> 6, lane = tid & 63;
        for (int rr = 0; rr < TOK / 4; ++rr) {
            const int r = wave * (TOK / 4) + rr;
            const float2 v = *(const float2*)&ebuf[r * 128 + lane * 2];
            float s  = v.x + v.y;
            float ss = v.x * v.x + v.y * v.y;
            #pragma unroll
            for (int off = 32; off >= 1; off >>= 1) {
                s  += __shfl_xor(s, off);
                ss += __shfl_xor(ss, off);
            }
            if (lane == 0) {
                const float m   = s * (1.f / 128.f);
                const float var = ss * (1.f / 128.f) - m * m;
                stats[r * 2]     = m;
                stats[r * 2 + 1] = rsqrtf(var + 1e-3f);
            }
        }
    }
    __syncthreads();
    {
        const float gv = g2[c], b2v = b2[c];
        #pragma unroll
        for (int j = 0; j < 8; ++j) {
            const int r = rg * 8 + j;
            const float m = stats[r * 2], rs = stats[r * 2 + 1];
            out[(row0 + r) * 128 + c] = (ebuf[r * 128 + c] - m) * rs * gv + b2v;
        }
    }
}

extern "C" void kernel_launch(void* const* d_in, const int* in_sizes, int n_in,
                              void* d_out, int out_size, void* d_ws, size_t ws_size,
                              hipStream_t stream) {
    const float* spatial   = (const float*)d_in[0];
    const float* frequency = (const float*)d_in[1];
    const float* wavelet   = (const float*)d_in[2];
    const float* Ws  = (const float*)d_in[3];
    const float* bs  = (const float*)d_in[4];
    const float* Wf  = (const float*)d_in[5];
    const float* bf  = (const float*)d_in[6];
    const float* Ww  = (const float*)d_in[7];
    const float* bw  = (const float*)d_in[8];
    const float* g1  = (const float*)d_in[9];
    const float* b1  = (const float*)d_in[10];
    // d_in[11..14] = Wk, bk, Wq, bq — provably unused (corr is constant)
    const float* Wt  = (const float*)d_in[15];
    const float* bt  = (const float*)d_in[16];
    const float* Wg  = (const float*)d_in[17];
    const float* bg  = (const float*)d_in[18];
    const float* Wfu = (const float*)d_in[19];
    const float* bfu = (const float*)d_in[20];
    const float* Wdf = (const float*)d_in[21];
    const float* bdf = (const float*)d_in[22];
    const float* g2  = (const float*)d_in[23];
    const float* b2  = (const float*)d_in[24];

    float* out   = (float*)d_out;
    float* consts = out + 2097152;          // corr[72] + dw[24]
    float* enh0  = out + 2097248;
    float* enh1  = out + 4194400;
    float* enh2  = out + 6291552;

    const size_t smem_dom  = (8192 + TOK * 256 + TOK * 64 + TOK * 128 + 32) * sizeof(float);
    const size_t smem_fuse = (8192 + TOK * 128 + TOK * 128 + 32) * sizeof(float);
    const int nblk = 16384 / TOK;

    const_kernel<<<1, 128, 0, stream>>>(consts);
    domain_kernel<<<nblk, 256, smem_dom, stream>>>(spatial,   Ws, bs, g1, b1, Wt, bt, Wg, bg, enh0);
    domain_kernel<<<nblk, 256, smem_dom, stream>>>(frequency, Wf, bf, g1, b1, Wt, bt, Wg, bg, enh1);
    domain_kernel<<<nblk, 256, smem_dom, stream>>>(wavelet,   Ww, bw, g1, b1, Wt, bt, Wg, bg, enh2);
    fuse_kernel<<<nblk, 256, smem_fuse, stream>>>(enh0, enh1, enh2, Wfu, bfu, Wdf, bdf, g2, b2, out);
}

// Round 2
// 273.943 us; speedup vs baseline: 1.9062x; 1.9062x over previous
//
#include <hip/hip_runtime.h>
#include <math.h>

// CrossDomainBridge — MI355X fp32, register-tiled (round 2).
//
// Math shortcut (exact): softmax rows sum to 1 => corr == 1/2048, dw == 1/8,
// corr_mean == 1/2048; gate bias folds: bg_eff = bg + (1/2048)*sum(Wg[128:131]).
//
// Round-1 lesson: inner loops were ds_read-issue-bound (1 LDS read per FMA,
// VALUBusy 49%). Fix: 4x8 / 4x4 register tiles, K unrolled by 4, all LDS
// operand reads as b128. TOK=32 tokens/block, 256 threads.
//
// d_out layout (floats): out[2097152] corr[72] dw[24] enh0 enh1 enh2

#define TOK 32

__global__ void const_kernel(float* __restrict__ dst) {
    int i = threadIdx.x;
    if (i < 72) dst[i] = 4.8828125e-4f;        // corr = 1/2048
    else if (i < 96) dst[i] = 0.125f;          // dw = 1/8
}

// stage 2048 floats global->LDS (256 threads, float4)
__device__ __forceinline__ void stage2048(const float* __restrict__ g,
                                          float* __restrict__ s, int tid) {
    const float4* gv = (const float4*)g;
    float4* sv = (float4*)s;
    sv[tid]       = gv[tid];
    sv[tid + 256] = gv[tid + 256];
}

// acc[4][4] += A[r0..r0+3][kb..kb+15] @ W[0..15][c0..c0+3]
// Abase points at &A[0][kb]; AS = A row stride (floats). W chunk is [16][128].
template <int AS>
__device__ __forceinline__ void gemm_chunk16(const float* __restrict__ Abase,
                                             const float* __restrict__ Wb,
                                             int r0, int c0, float acc[4][4]) {
    #pragma unroll
    for (int k4 = 0; k4 < 4; ++k4) {
        float ar[4][4];
        #pragma unroll
        for (int i = 0; i < 4; ++i) {
            const float4 v = *(const float4*)&Abase[(r0 + i) * AS + k4 * 4];
            ar[i][0] = v.x; ar[i][1] = v.y; ar[i][2] = v.z; ar[i][3] = v.w;
        }
        #pragma unroll
        for (int kk = 0; kk < 4; ++kk) {
            const float4 w = *(const float4*)&Wb[(k4 * 4 + kk) * 128 + c0];
            #pragma unroll
            for (int i = 0; i < 4; ++i) {
                acc[i][0] += ar[i][kk] * w.x;
                acc[i][1] += ar[i][kk] * w.y;
                acc[i][2] += ar[i][kk] * w.z;
                acc[i][3] += ar[i][kk] * w.w;
            }
        }
    }
}

// One domain: enh = (a@Wt+bt) * sigmoid((a@Wt+bt)@Wg0 + bg_eff) * 0.125
// where a = LN(x@Wd+bd, g1, b1)
__global__ __launch_bounds__(256) void domain_kernel(
    const float* __restrict__ x,    // [16384,64]
    const float* __restrict__ Wd,   // [64,256]
    const float* __restrict__ bd,   // [256]
    const float* __restrict__ g1,   // [256]
    const float* __restrict__ b1,   // [256]
    const float* __restrict__ Wt,   // [256,128]
    const float* __restrict__ bt,   // [128]
    const float* __restrict__ Wg,   // [131,128]
    const float* __restrict__ bg,   // [128]
    float* __restrict__ enh)        // [16384,128]
{
    extern __shared__ float lds[];
    float* abuf  = lds;               // [32][256] = 8192
    float* ubuf  = abuf + 8192;       // union: xbuf [32][64] / tbuf [32][128]
    float* Wbuf  = ubuf + 4096;       // 2048
    float* stats = Wbuf + 2048;       // 64
    float* xbuf  = ubuf;
    float* tbuf  = ubuf;

    const int tid  = threadIdx.x;
    const int row0 = blockIdx.x * TOK;

    // stage x rows: 2048 floats
    {
        const float4* xg = (const float4*)(x + row0 * 64);
        float4* xs = (float4*)xbuf;
        #pragma unroll
        for (int j = 0; j < 2; ++j) xs[tid + j * 256] = xg[tid + j * 256];
    }

    // ---- Phase A: a_raw = x @ Wd + bd. Tile: 8 cols x 4 rows / thread ----
    {
        const int ctA = tid & 31;      // 32 col-threads * 8 cols = 256
        const int rtA = tid >> 5;      // 8 row-threads * 4 rows = 32
        const int c0A = ctA * 8;
        const int r0A = rtA * 4;
        float acc[4][8];
        {
            const float4 b0 = *(const float4*)&bd[c0A];
            const float4 b4 = *(const float4*)&bd[c0A + 4];
            #pragma unroll
            for (int i = 0; i < 4; ++i) {
                acc[i][0] = b0.x; acc[i][1] = b0.y; acc[i][2] = b0.z; acc[i][3] = b0.w;
                acc[i][4] = b4.x; acc[i][5] = b4.y; acc[i][6] = b4.z; acc[i][7] = b4.w;
            }
        }
        #pragma unroll 1
        for (int ch = 0; ch < 8; ++ch) {          // K=64 in chunks of 8
            stage2048(Wd + ch * 2048, Wbuf, tid); // [8][256]
            __syncthreads();
            const int kb = ch * 8;
            #pragma unroll
            for (int k4 = 0; k4 < 2; ++k4) {
                float xr[4][4];
                #pragma unroll
                for (int i = 0; i < 4; ++i) {
                    const float4 v = *(const float4*)&xbuf[(r0A + i) * 64 + kb + k4 * 4];
                    xr[i][0] = v.x; xr[i][1] = v.y; xr[i][2] = v.z; xr[i][3] = v.w;
                }
                #pragma unroll
                for (int kk = 0; kk < 4; ++kk) {
                    const float4 w0 = *(const float4*)&Wbuf[(k4 * 4 + kk) * 256 + c0A];
                    const float4 w1 = *(const float4*)&Wbuf[(k4 * 4 + kk) * 256 + c0A + 4];
                    #pragma unroll
                    for (int i = 0; i < 4; ++i) {
                        acc[i][0] += xr[i][kk] * w0.x;
                        acc[i][1] += xr[i][kk] * w0.y;
                        acc[i][2] += xr[i][kk] * w0.z;
                        acc[i][3] += xr[i][kk] * w0.w;
                        acc[i][4] += xr[i][kk] * w1.x;
                        acc[i][5] += xr[i][kk] * w1.y;
                        acc[i][6] += xr[i][kk] * w1.z;
                        acc[i][7] += xr[i][kk] * w1.w;
                    }
                }
            }
            __syncthreads();
        }
        #pragma unroll
        for (int i = 0; i < 4; ++i) {
            *(float4*)&abuf[(r0A + i) * 256 + c0A] =
                make_float4(acc[i][0], acc[i][1], acc[i][2], acc[i][3]);
            *(float4*)&abuf[(r0A + i) * 256 + c0A + 4] =
                make_float4(acc[i][4], acc[i][5], acc[i][6], acc[i][7]);
        }
    }
    __syncthreads();

    // ---- LN stats per row ----
    {
        const int wave = tid >> 6, lane = tid & 63;
        #pragma unroll 1
        for (int rr = 0; rr < 8; ++rr) {
            const int r = wave * 8 + rr;
            const float4 v = *(const float4*)&abuf[r * 256 + lane * 4];
            float s  = v.x + v.y + v.z + v.w;
            float ss = v.x * v.x + v.y * v.y + v.z * v.z + v.w * v.w;
            #pragma unroll
            for (int off = 32; off >= 1; off >>= 1) {
                s  += __shfl_xor(s, off);
                ss += __shfl_xor(ss, off);
            }
            if (lane == 0) {
                const float m   = s * (1.f / 256.f);
                const float var = ss * (1.f / 256.f) - m * m;
                stats[r * 2]     = m;
                stats[r * 2 + 1] = rsqrtf(var + 1e-3f);
            }
        }
    }
    __syncthreads();
    // normalize in place (float4 over 8192 elements)
    {
        #pragma unroll
        for (int jj = 0; jj < 8; ++jj) {
            const int j = tid + jj * 256;
            const int r = j >> 6;
            const int c = (j & 63) * 4;
            float4 v = ((float4*)abuf)[j];
            const float m = stats[2 * r], rs = stats[2 * r + 1];
            const float4 g  = *(const float4*)&g1[c];
            const float4 bb = *(const float4*)&b1[c];
            v.x = (v.x - m) * rs * g.x + bb.x;
            v.y = (v.y - m) * rs * g.y + bb.y;
            v.z = (v.z - m) * rs * g.z + bb.z;
            v.w = (v.w - m) * rs * g.w + bb.w;
            ((float4*)abuf)[j] = v;
        }
    }
    __syncthreads();

    // ---- Phase T: t = a @ Wt + bt. Tile: 4 cols x 4 rows ----
    const int ct = tid & 31;     // 32 col-threads * 4 cols = 128
    const int rt = tid >> 5;     // 8 row-threads * 4 rows = 32
    const int c0 = ct * 4;
    const int r0 = rt * 4;
    float tacc[4][4];
    {
        const float4 b4 = *(const float4*)&bt[c0];
        #pragma unroll
        for (int i = 0; i < 4; ++i) {
            tacc[i][0] = b4.x; tacc[i][1] = b4.y; tacc[i][2] = b4.z; tacc[i][3] = b4.w;
        }
    }
    #pragma unroll 1
    for (int ch = 0; ch < 16; ++ch) {              // K=256 in chunks of 16
        stage2048(Wt + ch * 2048, Wbuf, tid);      // [16][128]
        __syncthreads();
        gemm_chunk16<256>(abuf + ch * 16, Wbuf, r0, c0, tacc);
        __syncthreads();
    }
    #pragma unroll
    for (int i = 0; i < 4; ++i)
        *(float4*)&tbuf[(r0 + i) * 128 + c0] =
            make_float4(tacc[i][0], tacc[i][1], tacc[i][2], tacc[i][3]);
    __syncthreads();

    // ---- Phase G: z = t @ Wg0 + bg_eff; enh = t * sigmoid(z) * 0.125 ----
    {
        float zacc[4][4];
        {
            const float4 bgv = *(const float4*)&bg[c0];
            const float4 w128 = *(const float4*)&Wg[128 * 128 + c0];
            const float4 w129 = *(const float4*)&Wg[129 * 128 + c0];
            const float4 w130 = *(const float4*)&Wg[130 * 128 + c0];
            const float z0 = bgv.x + 4.8828125e-4f * (w128.x + w129.x + w130.x);
            const float z1 = bgv.y + 4.8828125e-4f * (w128.y + w129.y + w130.y);
            const float z2 = bgv.z + 4.8828125e-4f * (w128.z + w129.z + w130.z);
            const float z3 = bgv.w + 4.8828125e-4f * (w128.w + w129.w + w130.w);
            #pragma unroll
            for (int i = 0; i < 4; ++i) {
                zacc[i][0] = z0; zacc[i][1] = z1; zacc[i][2] = z2; zacc[i][3] = z3;
            }
        }
        #pragma unroll 1
        for (int ch = 0; ch < 8; ++ch) {           // K=128 in chunks of 16
            stage2048(Wg + ch * 2048, Wbuf, tid);
            __syncthreads();
            gemm_chunk16<128>(tbuf + ch * 16, Wbuf, r0, c0, zacc);
            __syncthreads();
        }
        #pragma unroll
        for (int i = 0; i < 4; ++i) {
            float4 o;
            o.x = tacc[i][0] * (1.f / (1.f + expf(-zacc[i][0]))) * 0.125f;
            o.y = tacc[i][1] * (1.f / (1.f + expf(-zacc[i][1]))) * 0.125f;
            o.z = tacc[i][2] * (1.f / (1.f + expf(-zacc[i][2]))) * 0.125f;
            o.w = tacc[i][3] * (1.f / (1.f + expf(-zacc[i][3]))) * 0.125f;
            *(float4*)&enh[(row0 + r0 + i) * 128 + c0] = o;
        }
    }
}

// fused = sum_d enh_d @ Wfu_d + bfu; out = LN(fused@Wdf+bdf, g2, b2)
__global__ __launch_bounds__(256) void fuse_kernel(
    const float* __restrict__ enh0, const float* __restrict__ enh1,
    const float* __restrict__ enh2,
    const float* __restrict__ Wfu, const float* __restrict__ bfu,
    const float* __restrict__ Wdf, const float* __restrict__ bdf,
    const float* __restrict__ g2,  const float* __restrict__ b2,
    float* __restrict__ out)
{
    extern __shared__ float lds[];
    float* ebuf  = lds;               // [32][128] = 4096
    float* fbuf  = ebuf + 4096;       // [32][128] = 4096
    float* Wbuf  = fbuf + 4096;       // 2048
    float* stats = Wbuf + 2048;       // 64

    const int tid  = threadIdx.x;
    const int row0 = blockIdx.x * TOK;
    const int ct = tid & 31;
    const int rt = tid >> 5;
    const int c0 = ct * 4;
    const int r0 = rt * 4;

    float facc[4][4];
    {
        const float4 b4 = *(const float4*)&bfu[c0];
        #pragma unroll
        for (int i = 0; i < 4; ++i) {
            facc[i][0] = b4.x; facc[i][1] = b4.y; facc[i][2] = b4.z; facc[i][3] = b4.w;
        }
    }
    const float* enhs[3] = {enh0, enh1, enh2};
    #pragma unroll 1
    for (int d = 0; d < 3; ++d) {
        {   // stage enh_d tile: 4096 floats
            const float4* eg = (const float4*)(enhs[d] + row0 * 128);
            float4* es = (float4*)ebuf;
            #pragma unroll
            for (int j = 0; j < 4; ++j) es[tid + j * 256] = eg[tid + j * 256];
        }
        #pragma unroll 1
        for (int ch = 0; ch < 8; ++ch) {           // K=128 in chunks of 16
            stage2048(Wfu + d * 16384 + ch * 2048, Wbuf, tid);
            __syncthreads();
            gemm_chunk16<128>(ebuf + ch * 16, Wbuf, r0, c0, facc);
            __syncthreads();
        }
    }
    #pragma unroll
    for (int i = 0; i < 4; ++i)
        *(float4*)&fbuf[(r0 + i) * 128 + c0] =
            make_float4(facc[i][0], facc[i][1], facc[i][2], facc[i][3]);
    __syncthreads();

    // df = fused @ Wdf + bdf
    float dacc[4][4];
    {
        const float4 b4 = *(const float4*)&bdf[c0];
        #pragma unroll
        for (int i = 0; i < 4; ++i) {
            dacc[i][0] = b4.x; dacc[i][1] = b4.y; dacc[i][2] = b4.z; dacc[i][3] = b4.w;
        }
    }
    #pragma unroll 1
    for (int ch = 0; ch < 8; ++ch) {
        stage2048(Wdf + ch * 2048, Wbuf, tid);
        __syncthreads();
        gemm_chunk16<128>(fbuf + ch * 16, Wbuf, r0, c0, dacc);
        __syncthreads();
    }
    #pragma unroll
    for (int i = 0; i < 4; ++i)
        *(float4*)&ebuf[(r0 + i) * 128 + c0] =
            make_float4(dacc[i][0], dacc[i][1], dacc[i][2], dacc[i][3]);
    __syncthreads();

    // LN stats over 128 per row
    {
        const int wave = tid >> 6, lane = tid & 63;
        #pragma unroll 1
        for (int rr = 0; rr < 8; ++rr) {
            const int r = wave * 8 + rr;
            const float2 v = *(const float2*)&ebuf[r * 128 + lane * 2];
            float s  = v.x + v.y;
            float ss = v.x * v.x + v.y * v.y;
            #pragma unroll
            for (int off = 32; off >= 1; off >>= 1) {
                s  += __shfl_xor(s, off);
                ss += __shfl_xor(ss, off);
            }
            if (lane == 0) {
                const float m   = s * (1.f / 128.f);
                const float var = ss * (1.f / 128.f) - m * m;
                stats[r * 2]     = m;
                stats[r * 2 + 1] = rsqrtf(var + 1e-3f);
            }
        }
    }
    __syncthreads();
    {
        const float4 g4 = *(const float4*)&g2[c0];
        const float4 b4 = *(const float4*)&b2[c0];
        #pragma unroll
        for (int i = 0; i < 4; ++i) {
            const int r = r0 + i;
            const float m = stats[r * 2], rs = stats[r * 2 + 1];
            float4 o;
            o.x = (dacc[i][0] - m) * rs * g4.x + b4.x;
            o.y = (dacc[i][1] - m) * rs * g4.y + b4.y;
            o.z = (dacc[i][2] - m) * rs * g4.z + b4.z;
            o.w = (dacc[i][3] - m) * rs * g4.w + b4.w;
            *(float4*)&out[(row0 + r) * 128 + c0] = o;
        }
    }
}

extern "C" void kernel_launch(void* const* d_in, const int* in_sizes, int n_in,
                              void* d_out, int out_size, void* d_ws, size_t ws_size,
                              hipStream_t stream) {
    const float* spatial   = (const float*)d_in[0];
    const float* frequency = (const float*)d_in[1];
    const float* wavelet   = (const float*)d_in[2];
    const float* Ws  = (const float*)d_in[3];
    const float* bs  = (const float*)d_in[4];
    const float* Wf  = (const float*)d_in[5];
    const float* bf  = (const float*)d_in[6];
    const float* Ww  = (const float*)d_in[7];
    const float* bw  = (const float*)d_in[8];
    const float* g1  = (const float*)d_in[9];
    const float* b1  = (const float*)d_in[10];
    // d_in[11..14] = Wk, bk, Wq, bq — provably unused (corr is constant)
    const float* Wt  = (const float*)d_in[15];
    const float* bt  = (const float*)d_in[16];
    const float* Wg  = (const float*)d_in[17];
    const float* bg  = (const float*)d_in[18];
    const float* Wfu = (const float*)d_in[19];
    const float* bfu = (const float*)d_in[20];
    const float* Wdf = (const float*)d_in[21];
    const float* bdf = (const float*)d_in[22];
    const float* g2  = (const float*)d_in[23];
    const float* b2  = (const float*)d_in[24];

    float* out    = (float*)d_out;
    float* consts = out + 2097152;          // corr[72] + dw[24]
    float* enh0   = out + 2097248;
    float* enh1   = out + 4194400;
    float* enh2   = out + 6291552;

    const size_t smem_dom  = 14400 * sizeof(float);   // 57.6 KB
    const size_t smem_fuse = 10304 * sizeof(float);   // 41.2 KB
    const int nblk = 16384 / TOK;                     // 512

    const_kernel<<<1, 128, 0, stream>>>(consts);
    domain_kernel<<<nblk, 256, smem_dom, stream>>>(spatial,   Ws, bs, g1, b1, Wt, bt, Wg, bg, enh0);
    domain_kernel<<<nblk, 256, smem_dom, stream>>>(frequency, Wf, bf, g1, b1, Wt, bt, Wg, bg, enh1);
    domain_kernel<<<nblk, 256, smem_dom, stream>>>(wavelet,   Ww, bw, g1, b1, Wt, bt, Wg, bg, enh2);
    fuse_kernel<<<nblk, 256, smem_fuse, stream>>>(enh0, enh1, enh2, Wfu, bfu, Wdf, bdf, g2, b2, out);
}

// Round 3
// 257.343 us; speedup vs baseline: 2.0292x; 1.0645x over previous
//
#include <hip/hip_runtime.h>
#include <math.h>

// CrossDomainBridge — MI355X fp32 mega-kernel (round 3).
//
// Math shortcut (exact): softmax rows sum to 1 => corr == 1/2048, dw == 1/8,
// corr_mean == 1/2048; gate bias folds: bg_eff = bg + (1/2048)*sum(Wg[128:131]).
//
// Round-2 lesson: 2 barriers/chunk + un-overlapped weight staging at 20%
// occupancy => latency-bound (VALUBusy 34%). Fix: single fused kernel
// (fuse-GEMM accumulated in registers across the 3 domains — no enh re-read),
// double-buffered weight staging (1 barrier/chunk, load hides under FMA),
// phase-A retile c0=(tid&63)*4 to kill 8-way W-read bank conflicts.
// LDS = 64KB exactly: abuf 8192f + ubuf 4096f + Wbuf 2x2048f. 2 blocks/CU.
//
// d_out layout (floats): out[2097152] corr[72] dw[24] enh0 enh1 enh2

#define TOK 32

__device__ __forceinline__ void stage2048(const float* __restrict__ g,
                                          float* __restrict__ s, int tid) {
    const float4* gv = (const float4*)g;
    float4* sv = (float4*)s;
    sv[tid]       = gv[tid];
    sv[tid + 256] = gv[tid + 256];
}

// acc[4][4] += A[r0..r0+3][0..15] @ W[0..15][c0..c0+3]; W chunk is [16][128].
template <int AS>
__device__ __forceinline__ void gemm_chunk16(const float* __restrict__ Abase,
                                             const float* __restrict__ Wb,
                                             int r0, int c0, float acc[4][4]) {
    #pragma unroll
    for (int k4 = 0; k4 < 4; ++k4) {
        float ar[4][4];
        #pragma unroll
        for (int i = 0; i < 4; ++i) {
            const float4 v = *(const float4*)&Abase[(r0 + i) * AS + k4 * 4];
            ar[i][0] = v.x; ar[i][1] = v.y; ar[i][2] = v.z; ar[i][3] = v.w;
        }
        #pragma unroll
        for (int kk = 0; kk < 4; ++kk) {
            const float4 w = *(const float4*)&Wb[(k4 * 4 + kk) * 128 + c0];
            #pragma unroll
            for (int i = 0; i < 4; ++i) {
                acc[i][0] += ar[i][kk] * w.x;
                acc[i][1] += ar[i][kk] * w.y;
                acc[i][2] += ar[i][kk] * w.z;
                acc[i][3] += ar[i][kk] * w.w;
            }
        }
    }
}

// One domain: a = LN(x@Wd+bd); t = a@Wt+bt; enh = t*sigmoid(t@Wg0+bg_eff)/8;
// facc += enh @ Wfu_d. enh also written to global.
__device__ __forceinline__ void process_domain(
    const float* __restrict__ x, const float* __restrict__ Wd,
    const float* __restrict__ bd,
    const float* __restrict__ g1v, const float* __restrict__ b1v,
    const float* __restrict__ Wt, const float* __restrict__ bt,
    const float* __restrict__ Wg, const float4 zinit,
    const float* __restrict__ Wfu_d,
    float* __restrict__ enh,
    float* __restrict__ abuf, float* __restrict__ ubuf, float* __restrict__ Wbuf,
    int tid, int row0, float facc[4][4])
{
    // stage x tile (2048 floats) + Wd chunk0
    {
        const float4* xg = (const float4*)(x + row0 * 64);
        float4* xs = (float4*)ubuf;
        xs[tid]       = xg[tid];
        xs[tid + 256] = xg[tid + 256];
    }
    stage2048(Wd, Wbuf, tid);
    __syncthreads();

    // ---- Phase A: a_raw = x @ Wd + bd. Tile 8 rows x 4 cols ----
    // c0A consecutive b128 W-reads (conflict-free); A-reads wave-broadcast.
    const int c0A = (tid & 63) * 4;
    const int r0A = (tid >> 6) * 8;
    float acc[8][4];
    {
        const float4 bv = *(const float4*)&bd[c0A];
        #pragma unroll
        for (int i = 0; i < 8; ++i) {
            acc[i][0] = bv.x; acc[i][1] = bv.y; acc[i][2] = bv.z; acc[i][3] = bv.w;
        }
    }
    #pragma unroll 1
    for (int ch = 0; ch < 8; ++ch) {                   // K=64, 8 rows of Wd per chunk
        if (ch < 7) stage2048(Wd + (ch + 1) * 2048, Wbuf + ((ch + 1) & 1) * 2048, tid);
        const float* Wb = Wbuf + (ch & 1) * 2048;      // [8][256]
        const int kb = ch * 8;
        #pragma unroll
        for (int k4 = 0; k4 < 2; ++k4) {
            float xr[8][4];
            #pragma unroll
            for (int i = 0; i < 8; ++i) {
                const float4 v = *(const float4*)&ubuf[(r0A + i) * 64 + kb + k4 * 4];
                xr[i][0] = v.x; xr[i][1] = v.y; xr[i][2] = v.z; xr[i][3] = v.w;
            }
            #pragma unroll
            for (int kk = 0; kk < 4; ++kk) {
                const float4 w = *(const float4*)&Wb[(k4 * 4 + kk) * 256 + c0A];
                #pragma unroll
                for (int i = 0; i < 8; ++i) {
                    acc[i][0] += xr[i][kk] * w.x;
                    acc[i][1] += xr[i][kk] * w.y;
                    acc[i][2] += xr[i][kk] * w.z;
                    acc[i][3] += xr[i][kk] * w.w;
                }
            }
        }
        __syncthreads();
    }
    #pragma unroll
    for (int i = 0; i < 8; ++i)
        *(float4*)&abuf[(r0A + i) * 256 + c0A] =
            make_float4(acc[i][0], acc[i][1], acc[i][2], acc[i][3]);

    stage2048(Wt, Wbuf, tid);          // Wt chunk0 hides under LN
    __syncthreads();                   // abuf stores visible

    float* stats = Wbuf + 2048;        // buf1 region — free until T-loop ch=0
    {
        const int wave = tid >> 6, lane = tid & 63;
        #pragma unroll 1
        for (int rr = 0; rr < 8; ++rr) {
            const int r = wave * 8 + rr;
            const float4 v = *(const float4*)&abuf[r * 256 + lane * 4];
            float s  = v.x + v.y + v.z + v.w;
            float ss = v.x * v.x + v.y * v.y + v.z * v.z + v.w * v.w;
            #pragma unroll
            for (int off = 32; off >= 1; off >>= 1) {
                s  += __shfl_xor(s, off);
                ss += __shfl_xor(ss, off);
            }
            if (lane == 0) {
                const float m   = s * (1.f / 256.f);
                const float var = ss * (1.f / 256.f) - m * m;
                stats[r * 2]     = m;
                stats[r * 2 + 1] = rsqrtf(var + 1e-3f);
            }
        }
    }
    __syncthreads();
    {   // normalize in place
        #pragma unroll
        for (int jj = 0; jj < 8; ++jj) {
            const int j = tid + jj * 256;
            const int r = j >> 6;
            const int c = (j & 63) * 4;
            float4 v = ((float4*)abuf)[j];
            const float m = stats[2 * r], rs = stats[2 * r + 1];
            const float4 g  = *(const float4*)&g1v[c];
            const float4 bb = *(const float4*)&b1v[c];
            v.x = (v.x - m) * rs * g.x + bb.x;
            v.y = (v.y - m) * rs * g.y + bb.y;
            v.z = (v.z - m) * rs * g.z + bb.z;
            v.w = (v.w - m) * rs * g.w + bb.w;
            ((float4*)abuf)[j] = v;
        }
    }
    __syncthreads();

    // ---- Phase T: t = a @ Wt + bt. Tile 4x4 ----
    const int c0 = (tid & 31) * 4;
    const int r0 = (tid >> 5) * 4;
    float tacc[4][4];
    {
        const float4 bv = *(const float4*)&bt[c0];
        #pragma unroll
        for (int i = 0; i < 4; ++i) {
            tacc[i][0] = bv.x; tacc[i][1] = bv.y; tacc[i][2] = bv.z; tacc[i][3] = bv.w;
        }
    }
    #pragma unroll 1
    for (int ch = 0; ch < 16; ++ch) {                  // K=256, 16 rows/chunk
        if (ch < 15) stage2048(Wt + (ch + 1) * 2048, Wbuf + ((ch + 1) & 1) * 2048, tid);
        gemm_chunk16<256>(abuf + ch * 16, Wbuf + (ch & 1) * 2048, r0, c0, tacc);
        __syncthreads();
    }
    #pragma unroll
    for (int i = 0; i < 4; ++i)
        *(float4*)&ubuf[(r0 + i) * 128 + c0] =
            make_float4(tacc[i][0], tacc[i][1], tacc[i][2], tacc[i][3]);
    stage2048(Wg, Wbuf, tid);
    __syncthreads();

    // ---- Phase G: z = t @ Wg0 + bg_eff ----
    float zacc[4][4];
    #pragma unroll
    for (int i = 0; i < 4; ++i) {
        zacc[i][0] = zinit.x; zacc[i][1] = zinit.y;
        zacc[i][2] = zinit.z; zacc[i][3] = zinit.w;
    }
    #pragma unroll 1
    for (int ch = 0; ch < 8; ++ch) {                   // K=128
        if (ch < 7) stage2048(Wg + (ch + 1) * 2048, Wbuf + ((ch + 1) & 1) * 2048, tid);
        gemm_chunk16<128>(ubuf + ch * 16, Wbuf + (ch & 1) * 2048, r0, c0, zacc);
        __syncthreads();
    }
    // enh = t * sigmoid(z) * 0.125 -> global + ubuf (t is dead past last barrier)
    float eacc[4][4];
    #pragma unroll
    for (int i = 0; i < 4; ++i) {
        eacc[i][0] = tacc[i][0] * (1.f / (1.f + expf(-zacc[i][0]))) * 0.125f;
        eacc[i][1] = tacc[i][1] * (1.f / (1.f + expf(-zacc[i][1]))) * 0.125f;
        eacc[i][2] = tacc[i][2] * (1.f / (1.f + expf(-zacc[i][2]))) * 0.125f;
        eacc[i][3] = tacc[i][3] * (1.f / (1.f + expf(-zacc[i][3]))) * 0.125f;
        *(float4*)&enh[(row0 + r0 + i) * 128 + c0] =
            make_float4(eacc[i][0], eacc[i][1], eacc[i][2], eacc[i][3]);
        *(float4*)&ubuf[(r0 + i) * 128 + c0] =
            make_float4(eacc[i][0], eacc[i][1], eacc[i][2], eacc[i][3]);
    }
    stage2048(Wfu_d, Wbuf, tid);
    __syncthreads();

    // ---- Fuse accumulation: facc += enh_d @ Wfu_d ----
    #pragma unroll 1
    for (int ch = 0; ch < 8; ++ch) {                   // K=128
        if (ch < 7) stage2048(Wfu_d + (ch + 1) * 2048, Wbuf + ((ch + 1) & 1) * 2048, tid);
        gemm_chunk16<128>(ubuf + ch * 16, Wbuf + (ch & 1) * 2048, r0, c0, facc);
        __syncthreads();
    }
}

__global__ __launch_bounds__(256) void mega_kernel(
    const float* __restrict__ x0, const float* __restrict__ x1,
    const float* __restrict__ x2,
    const float* __restrict__ Wd0, const float* __restrict__ bd0,
    const float* __restrict__ Wd1, const float* __restrict__ bd1,
    const float* __restrict__ Wd2, const float* __restrict__ bd2,
    const float* __restrict__ g1, const float* __restrict__ b1,
    const float* __restrict__ Wt, const float* __restrict__ bt,
    const float* __restrict__ Wg, const float* __restrict__ bg,
    const float* __restrict__ Wfu, const float* __restrict__ bfu,
    const float* __restrict__ Wdf, const float* __restrict__ bdf,
    const float* __restrict__ g2, const float* __restrict__ b2,
    float* __restrict__ out, float* __restrict__ consts,
    float* __restrict__ e0, float* __restrict__ e1, float* __restrict__ e2)
{
    extern __shared__ float lds[];
    float* abuf = lds;            // 8192 floats: [32][256] a / [32][128] fused
    float* ubuf = abuf + 8192;    // 4096 floats: x / t / enh / df
    float* Wbuf = ubuf + 4096;    // 2 x 2048 floats: weight double-buffer

    const int tid  = threadIdx.x;
    const int row0 = blockIdx.x * TOK;

    if (blockIdx.x == 0) {
        if (tid < 72) consts[tid] = 4.8828125e-4f;       // corr = 1/2048
        else if (tid < 96) consts[tid] = 0.125f;         // dw = 1/8
    }

    const int c0 = (tid & 31) * 4;
    const int r0 = (tid >> 5) * 4;

    // folded gate bias: bg_eff = bg + (1/2048)*sum(Wg[128:131])
    float4 zinit;
    {
        const float4 bgv  = *(const float4*)&bg[c0];
        const float4 w128 = *(const float4*)&Wg[128 * 128 + c0];
        const float4 w129 = *(const float4*)&Wg[129 * 128 + c0];
        const float4 w130 = *(const float4*)&Wg[130 * 128 + c0];
        zinit.x = bgv.x + 4.8828125e-4f * (w128.x + w129.x + w130.x);
        zinit.y = bgv.y + 4.8828125e-4f * (w128.y + w129.y + w130.y);
        zinit.z = bgv.z + 4.8828125e-4f * (w128.z + w129.z + w130.z);
        zinit.w = bgv.w + 4.8828125e-4f * (w128.w + w129.w + w130.w);
    }

    float facc[4][4];
    {
        const float4 bv = *(const float4*)&bfu[c0];
        #pragma unroll
        for (int i = 0; i < 4; ++i) {
            facc[i][0] = bv.x; facc[i][1] = bv.y; facc[i][2] = bv.z; facc[i][3] = bv.w;
        }
    }

    process_domain(x0, Wd0, bd0, g1, b1, Wt, bt, Wg, zinit, Wfu,
                   e0, abuf, ubuf, Wbuf, tid, row0, facc);
    process_domain(x1, Wd1, bd1, g1, b1, Wt, bt, Wg, zinit, Wfu + 16384,
                   e1, abuf, ubuf, Wbuf, tid, row0, facc);
    process_domain(x2, Wd2, bd2, g1, b1, Wt, bt, Wg, zinit, Wfu + 32768,
                   e2, abuf, ubuf, Wbuf, tid, row0, facc);

    // fused -> abuf as [32][128]
    #pragma unroll
    for (int i = 0; i < 4; ++i)
        *(float4*)&abuf[(r0 + i) * 128 + c0] =
            make_float4(facc[i][0], facc[i][1], facc[i][2], facc[i][3]);
    stage2048(Wdf, Wbuf, tid);
    __syncthreads();

    // ---- df = fused @ Wdf + bdf ----
    float dacc[4][4];
    {
        const float4 bv = *(const float4*)&bdf[c0];
        #pragma unroll
        for (int i = 0; i < 4; ++i) {
            dacc[i][0] = bv.x; dacc[i][1] = bv.y; dacc[i][2] = bv.z; dacc[i][3] = bv.w;
        }
    }
    #pragma unroll 1
    for (int ch = 0; ch < 8; ++ch) {
        if (ch < 7) stage2048(Wdf + (ch + 1) * 2048, Wbuf + ((ch + 1) & 1) * 2048, tid);
        gemm_chunk16<128>(abuf + ch * 16, Wbuf + (ch & 1) * 2048, r0, c0, dacc);
        __syncthreads();
    }

    // ---- final LN over 128 ----
    #pragma unroll
    for (int i = 0; i < 4; ++i)
        *(float4*)&ubuf[(r0 + i) * 128 + c0] =
            make_float4(dacc[i][0], dacc[i][1], dacc[i][2], dacc[i][3]);
    __syncthreads();
    float* stats = Wbuf;
    {
        const int wave = tid >> 6, lane = tid & 63;
        #pragma unroll 1
        for (int rr = 0; rr < 8; ++rr) {
            const int r = wave * 8 + rr;
            const float2 v = *(const float2*)&ubuf[r * 128 + lane * 2];
            float s  = v.x + v.y;
            float ss = v.x * v.x + v.y * v.y;
            #pragma unroll
            for (int off = 32; off >= 1; off >>= 1) {
                s  += __shfl_xor(s, off);
                ss += __shfl_xor(ss, off);
            }
            if (lane == 0) {
                const float m   = s * (1.f / 128.f);
                const float var = ss * (1.f / 128.f) - m * m;
                stats[r * 2]     = m;
                stats[r * 2 + 1] = rsqrtf(var + 1e-3f);
            }
        }
    }
    __syncthreads();
    {
        const float4 g4 = *(const float4*)&g2[c0];
        const float4 b4 = *(const float4*)&b2[c0];
        #pragma unroll
        for (int i = 0; i < 4; ++i) {
            const int r = r0 + i;
            const float m = stats[r * 2], rs = stats[r * 2 + 1];
            float4 o;
            o.x = (dacc[i][0] - m) * rs * g4.x + b4.x;
            o.y = (dacc[i][1] - m) * rs * g4.y + b4.y;
            o.z = (dacc[i][2] - m) * rs * g4.z + b4.z;
            o.w = (dacc[i][3] - m) * rs * g4.w + b4.w;
            *(float4*)&out[(row0 + r) * 128 + c0] = o;
        }
    }
}

extern "C" void kernel_launch(void* const* d_in, const int* in_sizes, int n_in,
                              void* d_out, int out_size, void* d_ws, size_t ws_size,
                              hipStream_t stream) {
    const float* spatial   = (const float*)d_in[0];
    const float* frequency = (const float*)d_in[1];
    const float* wavelet   = (const float*)d_in[2];
    const float* Ws  = (const float*)d_in[3];
    const float* bs  = (const float*)d_in[4];
    const float* Wf  = (const float*)d_in[5];
    const float* bf  = (const float*)d_in[6];
    const float* Ww  = (const float*)d_in[7];
    const float* bw  = (const float*)d_in[8];
    const float* g1  = (const float*)d_in[9];
    const float* b1  = (const float*)d_in[10];
    // d_in[11..14] = Wk, bk, Wq, bq — provably unused (corr is constant)
    const float* Wt  = (const float*)d_in[15];
    const float* bt  = (const float*)d_in[16];
    const float* Wg  = (const float*)d_in[17];
    const float* bg  = (const float*)d_in[18];
    const float* Wfu = (const float*)d_in[19];
    const float* bfu = (const float*)d_in[20];
    const float* Wdf = (const float*)d_in[21];
    const float* bdf = (const float*)d_in[22];
    const float* g2  = (const float*)d_in[23];
    const float* b2  = (const float*)d_in[24];

    float* out    = (float*)d_out;
    float* consts = out + 2097152;          // corr[72] + dw[24]
    float* enh0   = out + 2097248;
    float* enh1   = out + 4194400;
    float* enh2   = out + 6291552;

    const size_t smem = 16384 * sizeof(float);   // 64 KB exactly
    const int nblk = 16384 / TOK;                // 512

    mega_kernel<<<nblk, 256, smem, stream>>>(
        spatial, frequency, wavelet,
        Ws, bs, Wf, bf, Ww, bw, g1, b1,
        Wt, bt, Wg, bg, Wfu, bfu, Wdf, bdf, g2, b2,
        out, consts, enh0, enh1, enh2);
}

// Round 4
// 188.979 us; speedup vs baseline: 2.7632x; 1.3618x over previous
//
#include <hip/hip_runtime.h>
#include <math.h>

// CrossDomainBridge — MI355X split-bf16 MFMA mega-kernel (round 4).
//
// Math shortcut (exact): softmax rows sum to 1 => corr == 1/2048, dw == 1/8,
// corr_mean == 1/2048; gate bias folds: bg_eff = bg + (1/2048)*sum(Wg[128:131]).
//
// Round-3 lesson: fp32 vector path is LDS-pipe-bound (3x oversubscribed vs
// FMA). Switch to MFMA 16x16x32 bf16 with hi/lo split (3 products) for
// fp32-grade accuracy. Weights pre-packed once into d_ws (REQUIRES ws_size
// >= 655360 bytes) in fragment-linear lane order -> B-frags load straight
// global->VGPR. Activations in LDS as split bf16 planes, pitch K+8.
//
// d_out layout (floats): out[2097152] corr[72] dw[24] enh0 enh1 enh2

typedef __attribute__((ext_vector_type(8))) short short8;
typedef __attribute__((ext_vector_type(4))) float f32x4;
#define MFMA(a, b, c) __builtin_amdgcn_mfma_f32_16x16x32_bf16(a, b, c, 0, 0, 0)

#define NTOK 32

// ws layout (elems, bf16): each matrix [hi S][lo S]
#define WD0_B 0u
#define WD1_B 32768u
#define WD2_B 65536u
#define WT_B  98304u
#define WG_B  163840u
#define WF0_B 196608u
#define WF1_B 229376u
#define WF2_B 262144u
#define WDF_B 294912u

__device__ __forceinline__ unsigned short bf16rtn(float v) {
    unsigned u = __float_as_uint(v);
    unsigned r = u + 0x7FFFu + ((u >> 16) & 1u);
    return (unsigned short)(r >> 16);
}
__device__ __forceinline__ void split2(float v, unsigned short& h, unsigned short& l) {
    h = bf16rtn(v);
    float hf = __uint_as_float(((unsigned)h) << 16);
    l = bf16rtn(v - hf);
}
__device__ __forceinline__ float bf2f(unsigned short h) {
    return __uint_as_float(((unsigned)h) << 16);
}

// Pack weights into fragment-linear split-bf16: for matrix W[K][N], frag
// (nt,kc): lane holds W[kc*32+(lane>>4)*8 + j][nt*16+(lane&15)], j=0..7.
__global__ __launch_bounds__(256) void prep_kernel(
    const float* __restrict__ Ws, const float* __restrict__ Wf,
    const float* __restrict__ Ww, const float* __restrict__ Wt,
    const float* __restrict__ Wg, const float* __restrict__ Wfu,
    const float* __restrict__ Wdf, unsigned short* __restrict__ ws)
{
    int s = blockIdx.x * 256 + threadIdx.x;   // 0..20479 frag-lane slots
    const float* src; int K, N; unsigned base, S; int fi;
    if (s < 2048)      { src = Ws;            K = 64;  N = 256; base = WD0_B; S = 16384; fi = s; }
    else if (s < 4096) { src = Wf;            K = 64;  N = 256; base = WD1_B; S = 16384; fi = s - 2048; }
    else if (s < 6144) { src = Ww;            K = 64;  N = 256; base = WD2_B; S = 16384; fi = s - 4096; }
    else if (s < 10240){ src = Wt;            K = 256; N = 128; base = WT_B;  S = 32768; fi = s - 6144; }
    else if (s < 12288){ src = Wg;            K = 128; N = 128; base = WG_B;  S = 16384; fi = s - 10240; }
    else if (s < 14336){ src = Wfu;           K = 128; N = 128; base = WF0_B; S = 16384; fi = s - 12288; }
    else if (s < 16384){ src = Wfu + 16384;   K = 128; N = 128; base = WF1_B; S = 16384; fi = s - 14336; }
    else if (s < 18432){ src = Wfu + 32768;   K = 128; N = 128; base = WF2_B; S = 16384; fi = s - 16384; }
    else               { src = Wdf;           K = 128; N = 128; base = WDF_B; S = 16384; fi = s - 18432; }
    const int lane = fi & 63, frag = fi >> 6;
    const int KC = K >> 5;
    const int nt = frag / KC, kc = frag - nt * KC;
    const int n  = nt * 16 + (lane & 15);
    const int k0 = kc * 32 + (lane >> 4) * 8;
    short8 hv, lv;
    #pragma unroll
    for (int j = 0; j < 8; ++j) {
        unsigned short h, l;
        split2(src[(k0 + j) * N + n], h, l);
        hv[j] = (short)h; lv[j] = (short)l;
    }
    *(short8*)&ws[base + (unsigned)fi * 8]     = hv;
    *(short8*)&ws[base + S + (unsigned)fi * 8] = lv;
}

__global__ __launch_bounds__(512, 4) void mega_kernel(
    const float* __restrict__ x0, const float* __restrict__ x1,
    const float* __restrict__ x2,
    const float* __restrict__ bd0, const float* __restrict__ bd1,
    const float* __restrict__ bd2,
    const float* __restrict__ g1, const float* __restrict__ b1,
    const float* __restrict__ bt, const float* __restrict__ Wg,
    const float* __restrict__ bg, const float* __restrict__ bfu,
    const float* __restrict__ bdf, const float* __restrict__ g2,
    const float* __restrict__ b2,
    const unsigned short* __restrict__ ws,
    float* __restrict__ out, float* __restrict__ consts,
    float* __restrict__ e0, float* __restrict__ e1, float* __restrict__ e2)
{
    // LDS: split bf16 activation planes, pitch = K+8 (8 lanes/bank-set = b128 floor)
    __shared__ unsigned short xh[32 * 72],  xl[32 * 72];    //  9216 B
    __shared__ unsigned short ah[32 * 264], al[32 * 264];   // 33792 B
    __shared__ unsigned short th[32 * 136], tl[32 * 136];   // 17408 B  (t -> enh -> fused)
    __shared__ float psum[32 * 8];                          //  1024 B  [row][wn][2]

    const int tid = threadIdx.x, wave = tid >> 6, lane = tid & 63;
    const int lm = lane & 15, quad = lane >> 4;
    const int wn = wave & 3, wm = wave >> 2;     // 4 n-groups x 2 m-groups
    const int row0 = blockIdx.x * NTOK;

    if (blockIdx.x == 0) {
        if (tid < 72) consts[tid] = 4.8828125e-4f;      // corr = 1/2048
        else if (tid < 96) consts[tid] = 0.125f;        // dw = 1/8
    }

    // per-lane column sets + cached params
    int cA[4]; float g1c[4], b1c[4];
    #pragma unroll
    for (int i = 0; i < 4; ++i) { cA[i] = (wn * 4 + i) * 16 + lm; g1c[i] = g1[cA[i]]; b1c[i] = b1[cA[i]]; }
    int cT[2]; float btc[2], bgc[2], bdc[2], g2c[2], b2c[2];
    f32x4 facc[2];
    #pragma unroll
    for (int i = 0; i < 2; ++i) {
        const int c = (wn * 2 + i) * 16 + lm; cT[i] = c;
        btc[i] = bt[c];
        bgc[i] = bg[c] + 4.8828125e-4f * (Wg[16384 + c] + Wg[16512 + c] + Wg[16640 + c]);
        bdc[i] = bdf[c]; g2c[i] = g2[c]; b2c[i] = b2[c];
        const float bv = bfu[c];
        facc[i] = (f32x4){bv, bv, bv, bv};
    }

    const float* xs[3]  = {x0, x1, x2};
    const float* bds[3] = {bd0, bd1, bd2};
    float* es[3] = {e0, e1, e2};
    const unsigned WDB[3] = {WD0_B, WD1_B, WD2_B};
    const unsigned WFB[3] = {WF0_B, WF1_B, WF2_B};

    const int tokA = wm * 16 + lm;          // A-frag token for this lane

    for (int d = 0; d < 3; ++d) {
        __syncthreads();                    // prev-domain plane readers done
        {   // stage x split: 1 float4 per thread
            const int tok = tid >> 4, c4 = (tid & 15) * 4;
            const float4 v = *(const float4*)&xs[d][(row0 + tok) * 64 + c4];
            unsigned short h0, l0, h1, l1, h2, l2, h3, l3;
            split2(v.x, h0, l0); split2(v.y, h1, l1);
            split2(v.z, h2, l2); split2(v.w, h3, l3);
            *(ushort4*)&xh[tok * 72 + c4] = make_ushort4(h0, h1, h2, h3);
            *(ushort4*)&xl[tok * 72 + c4] = make_ushort4(l0, l1, l2, l3);
        }
        __syncthreads();

        // ---- Phase A: a_raw = x @ Wd + bd  (2 kc, 4 ntiles/wave) ----
        f32x4 acc[4];
        {
            const float* bdp = bds[d];
            #pragma unroll
            for (int i = 0; i < 4; ++i) { const float bv = bdp[cA[i]]; acc[i] = (f32x4){bv, bv, bv, bv}; }
        }
        #pragma unroll
        for (int kc = 0; kc < 2; ++kc) {
            const int k = kc * 32 + quad * 8;
            const short8 Ah = *(const short8*)&xh[tokA * 72 + k];
            const short8 Al = *(const short8*)&xl[tokA * 72 + k];
            #pragma unroll
            for (int i = 0; i < 4; ++i) {
                const unsigned short* bp = ws + WDB[d] + ((unsigned)((wn * 4 + i) * 2 + kc) * 64 + lane) * 8;
                const short8 Bh = *(const short8*)bp;
                const short8 Bl = *(const short8*)(bp + 16384);
                acc[i] = MFMA(Ah, Bh, acc[i]);
                acc[i] = MFMA(Al, Bh, acc[i]);
                acc[i] = MFMA(Ah, Bl, acc[i]);
            }
        }
        // LN stats from C-layout regs: rows wm*16+quad*4+r, cols cA[i]
        {
            float s[4], qq[4];
            #pragma unroll
            for (int r = 0; r < 4; ++r) {
                s[r] = 0.f; qq[r] = 0.f;
                #pragma unroll
                for (int i = 0; i < 4; ++i) { const float v = acc[i][r]; s[r] += v; qq[r] += v * v; }
            }
            #pragma unroll
            for (int off = 1; off < 16; off <<= 1) {
                #pragma unroll
                for (int r = 0; r < 4; ++r) { s[r] += __shfl_xor(s[r], off); qq[r] += __shfl_xor(qq[r], off); }
            }
            if (lm == 0) {
                #pragma unroll
                for (int r = 0; r < 4; ++r) {
                    const int row = wm * 16 + quad * 4 + r;
                    psum[row * 8 + wn * 2]     = s[r];
                    psum[row * 8 + wn * 2 + 1] = qq[r];
                }
            }
        }
        __syncthreads();
        // normalize + split-store a
        #pragma unroll
        for (int r = 0; r < 4; ++r) {
            const int row = wm * 16 + quad * 4 + r;
            float S = 0.f, Q = 0.f;
            #pragma unroll
            for (int w = 0; w < 4; ++w) { S += psum[row * 8 + w * 2]; Q += psum[row * 8 + w * 2 + 1]; }
            const float m  = S * (1.f / 256.f);
            const float rs = rsqrtf(Q * (1.f / 256.f) - m * m + 1e-3f);
            #pragma unroll
            for (int i = 0; i < 4; ++i) {
                const float v = (acc[i][r] - m) * rs * g1c[i] + b1c[i];
                unsigned short h, l; split2(v, h, l);
                ah[row * 264 + cA[i]] = h; al[row * 264 + cA[i]] = l;
            }
        }
        __syncthreads();

        // ---- Phase T: t = a @ Wt + bt (8 kc, 2 ntiles/wave, B prefetched) ----
        f32x4 tac[2];
        #pragma unroll
        for (int i = 0; i < 2; ++i) tac[i] = (f32x4){btc[i], btc[i], btc[i], btc[i]};
        {
            short8 Bh[2], Bl[2], Bh2[2], Bl2[2];
            #pragma unroll
            for (int i = 0; i < 2; ++i) {
                const unsigned short* bp = ws + WT_B + ((unsigned)((wn * 2 + i) * 8) * 64 + lane) * 8;
                Bh[i] = *(const short8*)bp; Bl[i] = *(const short8*)(bp + 32768);
            }
            #pragma unroll 1
            for (int kc = 0; kc < 8; ++kc) {
                if (kc < 7) {
                    #pragma unroll
                    for (int i = 0; i < 2; ++i) {
                        const unsigned short* bp = ws + WT_B + ((unsigned)((wn * 2 + i) * 8 + kc + 1) * 64 + lane) * 8;
                        Bh2[i] = *(const short8*)bp; Bl2[i] = *(const short8*)(bp + 32768);
                    }
                }
                const int k = kc * 32 + quad * 8;
                const short8 Ah = *(const short8*)&ah[tokA * 264 + k];
                const short8 Al = *(const short8*)&al[tokA * 264 + k];
                #pragma unroll
                for (int i = 0; i < 2; ++i) {
                    tac[i] = MFMA(Ah, Bh[i], tac[i]);
                    tac[i] = MFMA(Al, Bh[i], tac[i]);
                    tac[i] = MFMA(Ah, Bl[i], tac[i]);
                }
                #pragma unroll
                for (int i = 0; i < 2; ++i) { Bh[i] = Bh2[i]; Bl[i] = Bl2[i]; }
            }
        }
        // t -> split planes
        #pragma unroll
        for (int i = 0; i < 2; ++i)
            #pragma unroll
            for (int r = 0; r < 4; ++r) {
                const int row = wm * 16 + quad * 4 + r;
                unsigned short h, l; split2(tac[i][r], h, l);
                th[row * 136 + cT[i]] = h; tl[row * 136 + cT[i]] = l;
            }
        __syncthreads();

        // ---- Phase G: z = t @ Wg0 + bg_eff (4 kc) ----
        f32x4 zac[2];
        #pragma unroll
        for (int i = 0; i < 2; ++i) zac[i] = (f32x4){bgc[i], bgc[i], bgc[i], bgc[i]};
        #pragma unroll 1
        for (int kc = 0; kc < 4; ++kc) {
            const int k = kc * 32 + quad * 8;
            const short8 Ah = *(const short8*)&th[tokA * 136 + k];
            const short8 Al = *(const short8*)&tl[tokA * 136 + k];
            #pragma unroll
            for (int i = 0; i < 2; ++i) {
                const unsigned short* bp = ws + WG_B + ((unsigned)((wn * 2 + i) * 4 + kc) * 64 + lane) * 8;
                const short8 Bh = *(const short8*)bp;
                const short8 Bl = *(const short8*)(bp + 16384);
                zac[i] = MFMA(Ah, Bh, zac[i]);
                zac[i] = MFMA(Al, Bh, zac[i]);
                zac[i] = MFMA(Ah, Bl, zac[i]);
            }
        }
        // enh = t * sigmoid(z) * 0.125  -> global + (after barrier) planes
        float er[2][4];
        #pragma unroll
        for (int i = 0; i < 2; ++i)
            #pragma unroll
            for (int r = 0; r < 4; ++r) {
                const int row = wm * 16 + quad * 4 + r;
                const float tv = bf2f(th[row * 136 + cT[i]]) + bf2f(tl[row * 136 + cT[i]]);
                const float e  = tv * (1.f / (1.f + __expf(-zac[i][r]))) * 0.125f;
                er[i][r] = e;
                es[d][(row0 + row) * 128 + cT[i]] = e;
            }
        __syncthreads();                    // all t reads done before overwrite
        #pragma unroll
        for (int i = 0; i < 2; ++i)
            #pragma unroll
            for (int r = 0; r < 4; ++r) {
                const int row = wm * 16 + quad * 4 + r;
                unsigned short h, l; split2(er[i][r], h, l);
                th[row * 136 + cT[i]] = h; tl[row * 136 + cT[i]] = l;
            }
        __syncthreads();

        // ---- Fuse acc: facc += enh_d @ Wfu_d (4 kc) ----
        #pragma unroll 1
        for (int kc = 0; kc < 4; ++kc) {
            const int k = kc * 32 + quad * 8;
            const short8 Ah = *(const short8*)&th[tokA * 136 + k];
            const short8 Al = *(const short8*)&tl[tokA * 136 + k];
            #pragma unroll
            for (int i = 0; i < 2; ++i) {
                const unsigned short* bp = ws + WFB[d] + ((unsigned)((wn * 2 + i) * 4 + kc) * 64 + lane) * 8;
                const short8 Bh = *(const short8*)bp;
                const short8 Bl = *(const short8*)(bp + 16384);
                facc[i] = MFMA(Ah, Bh, facc[i]);
                facc[i] = MFMA(Al, Bh, facc[i]);
                facc[i] = MFMA(Ah, Bl, facc[i]);
            }
        }
    }

    __syncthreads();
    // fused -> split planes
    #pragma unroll
    for (int i = 0; i < 2; ++i)
        #pragma unroll
        for (int r = 0; r < 4; ++r) {
            const int row = wm * 16 + quad * 4 + r;
            unsigned short h, l; split2(facc[i][r], h, l);
            th[row * 136 + cT[i]] = h; tl[row * 136 + cT[i]] = l;
        }
    __syncthreads();

    // ---- df = fused @ Wdf + bdf (4 kc) ----
    f32x4 dac[2];
    #pragma unroll
    for (int i = 0; i < 2; ++i) dac[i] = (f32x4){bdc[i], bdc[i], bdc[i], bdc[i]};
    #pragma unroll 1
    for (int kc = 0; kc < 4; ++kc) {
        const int k = kc * 32 + quad * 8;
        const short8 Ah = *(const short8*)&th[tokA * 136 + k];
        const short8 Al = *(const short8*)&tl[tokA * 136 + k];
        #pragma unroll
        for (int i = 0; i < 2; ++i) {
            const unsigned short* bp = ws + WDF_B + ((unsigned)((wn * 2 + i) * 4 + kc) * 64 + lane) * 8;
            const short8 Bh = *(const short8*)bp;
            const short8 Bl = *(const short8*)(bp + 16384);
            dac[i] = MFMA(Ah, Bh, dac[i]);
            dac[i] = MFMA(Al, Bh, dac[i]);
            dac[i] = MFMA(Ah, Bl, dac[i]);
        }
    }
    // ---- final LN over 128 ----
    {
        float s[4], qq[4];
        #pragma unroll
        for (int r = 0; r < 4; ++r) {
            s[r] = dac[0][r] + dac[1][r];
            qq[r] = dac[0][r] * dac[0][r] + dac[1][r] * dac[1][r];
        }
        #pragma unroll
        for (int off = 1; off < 16; off <<= 1) {
            #pragma unroll
            for (int r = 0; r < 4; ++r) { s[r] += __shfl_xor(s[r], off); qq[r] += __shfl_xor(qq[r], off); }
        }
        if (lm == 0) {
            #pragma unroll
            for (int r = 0; r < 4; ++r) {
                const int row = wm * 16 + quad * 4 + r;
                psum[row * 8 + wn * 2]     = s[r];
                psum[row * 8 + wn * 2 + 1] = qq[r];
            }
        }
    }
    __syncthreads();
    #pragma unroll
    for (int r = 0; r < 4; ++r) {
        const int row = wm * 16 + quad * 4 + r;
        float S = 0.f, Q = 0.f;
        #pragma unroll
        for (int w = 0; w < 4; ++w) { S += psum[row * 8 + w * 2]; Q += psum[row * 8 + w * 2 + 1]; }
        const float m  = S * (1.f / 128.f);
        const float rs = rsqrtf(Q * (1.f / 128.f) - m * m + 1e-3f);
        #pragma unroll
        for (int i = 0; i < 2; ++i)
            out[(row0 + row) * 128 + cT[i]] = (dac[i][r] - m) * rs * g2c[i] + b2c[i];
    }
}

extern "C" void kernel_launch(void* const* d_in, const int* in_sizes, int n_in,
                              void* d_out, int out_size, void* d_ws, size_t ws_size,
                              hipStream_t stream) {
    const float* spatial   = (const float*)d_in[0];
    const float* frequency = (const float*)d_in[1];
    const float* wavelet   = (const float*)d_in[2];
    const float* Ws  = (const float*)d_in[3];
    const float* bs  = (const float*)d_in[4];
    const float* Wf  = (const float*)d_in[5];
    const float* bf  = (const float*)d_in[6];
    const float* Ww  = (const float*)d_in[7];
    const float* bw  = (const float*)d_in[8];
    const float* g1  = (const float*)d_in[9];
    const float* b1  = (const float*)d_in[10];
    // d_in[11..14] = Wk, bk, Wq, bq — provably unused (corr is constant)
    const float* Wt  = (const float*)d_in[15];
    const float* bt  = (const float*)d_in[16];
    const float* Wg  = (const float*)d_in[17];
    const float* bg  = (const float*)d_in[18];
    const float* Wfu = (const float*)d_in[19];
    const float* bfu = (const float*)d_in[20];
    const float* Wdf = (const float*)d_in[21];
    const float* bdf = (const float*)d_in[22];
    const float* g2  = (const float*)d_in[23];
    const float* b2  = (const float*)d_in[24];

    float* out    = (float*)d_out;
    float* consts = out + 2097152;          // corr[72] + dw[24]
    float* enh0   = out + 2097248;
    float* enh1   = out + 4194400;
    float* enh2   = out + 6291552;
    unsigned short* wsp = (unsigned short*)d_ws;   // needs 655360 B

    prep_kernel<<<80, 256, 0, stream>>>(Ws, Wf, Ww, Wt, Wg, Wfu, Wdf, wsp);
    mega_kernel<<<16384 / NTOK, 512, 0, stream>>>(
        spatial, frequency, wavelet, bs, bf, bw, g1, b1,
        bt, Wg, bg, bfu, bdf, g2, b2, wsp,
        out, consts, enh0, enh1, enh2);
}